// Round 3
// baseline (317.494 us; speedup 1.0000x reference)
//
#include <hip/hip_runtime.h>
#include <hip/hip_bf16.h>

#define D 256
#define BM 64
#define BK 64
#define LDK 72   // padded LDS k-stride (144B rows: 16B-aligned, 2-way bank alias = free)

typedef __attribute__((ext_vector_type(8))) __bf16 bf16x8;
typedef __attribute__((ext_vector_type(4))) float f32x4;

__device__ __forceinline__ float bf2f(unsigned short u) {
    union { unsigned int i; float f; } c; c.i = ((unsigned int)u) << 16; return c.f;
}
__device__ __forceinline__ unsigned short f2bf(float f) {
    __hip_bfloat16 h = __float2bfloat16(f);
    return *reinterpret_cast<unsigned short*>(&h);
}

// ======================= FAST PATH (fused, bf16 data path) =======================

// convert features fp32->bf16 (blocks [0,nbF)) and W -> Wt[c][k] bf16 (blocks [nbF,nbF+512))
__global__ void k_cvt_all(const float* __restrict__ uf, const float* __restrict__ itf,
                          const float* __restrict__ Wu, const float* __restrict__ Wi,
                          unsigned short* __restrict__ feat_bf,
                          unsigned short* __restrict__ Wt_u, unsigned short* __restrict__ Wt_i,
                          size_t nfU, size_t nfTot, int nbF) {
    int b = blockIdx.x;
    if (b < nbF) {
        size_t base = ((size_t)b * 256 + threadIdx.x) * 8;
        if (base < nfTot) {
            const float* s = (base < nfU) ? (uf + base) : (itf + (base - nfU));
            float4 f0 = *(const float4*)s;
            float4 f1 = *(const float4*)(s + 4);
            ushort4 o0, o1;
            o0.x = f2bf(f0.x); o0.y = f2bf(f0.y); o0.z = f2bf(f0.z); o0.w = f2bf(f0.w);
            o1.x = f2bf(f1.x); o1.y = f2bf(f1.y); o1.z = f2bf(f1.z); o1.w = f2bf(f1.w);
            ((ushort4*)(feat_bf + base))[0] = o0;
            ((ushort4*)(feat_bf + base))[1] = o1;
        }
    } else {
        int b2 = b - nbF;
        const float* W = (b2 < 256) ? Wu : Wi;
        unsigned short* Wt = (b2 < 256) ? Wt_u : Wt_i;
        int k = b2 & 255;
        int c = threadIdx.x;
        Wt[(size_t)c * 256 + k] = f2bf(W[(size_t)k * 256 + c]);
    }
}

// degree histogram for both sides in one dispatch
__global__ void k_hist2(const int* __restrict__ iu_e, int Eiu,
                        const int* __restrict__ ui_e, int Eui,
                        int* __restrict__ deg, int NU) {
    int e = blockIdx.x * blockDim.x + threadIdx.x;
    if (e < Eiu) {
        atomicAdd(&deg[iu_e[Eiu + e]], 1);
    } else if (e < Eiu + Eui) {
        int e2 = e - Eiu;
        atomicAdd(&deg[NU + ui_e[Eui + e2]], 1);
    }
}

// one block per side: serial-per-thread + block scan; writes rs[] and cursor init
__global__ void k_scan2(const int* __restrict__ deg,
                        int* __restrict__ rs_u, int* __restrict__ rs_i,
                        int* __restrict__ cur, int NU, int NI) {
    __shared__ int sh[1024];
    int t = threadIdx.x;
    int N        = (blockIdx.x == 0) ? NU : NI;
    const int* dg = (blockIdx.x == 0) ? deg : deg + NU;
    int* rs      = (blockIdx.x == 0) ? rs_u : rs_i;
    int* cu      = (blockIdx.x == 0) ? cur : cur + NU;
    int chunk = (N + 1023) >> 10;
    int lo = t * chunk;
    int hi = lo + chunk; if (hi > N) hi = N;
    int sum = 0;
    for (int j = lo; j < hi; j++) sum += dg[j];
    sh[t] = sum;
    __syncthreads();
    for (int off = 1; off < 1024; off <<= 1) {
        int add = (t >= off) ? sh[t - off] : 0;
        __syncthreads();
        sh[t] += add;
        __syncthreads();
    }
    int run = (t == 0) ? 0 : sh[t - 1];
    for (int j = lo; j < hi; j++) { cu[j] = run; run += dg[j]; rs[j + 1] = run; }
    if (t == 0) rs[0] = 0;
}

__global__ void k_fill2(const int* __restrict__ iu_e, int Eiu,
                        const int* __restrict__ ui_e, int Eui,
                        int* __restrict__ cur, int NU,
                        int* __restrict__ csr_u, int* __restrict__ csr_i) {
    int e = blockIdx.x * blockDim.x + threadIdx.x;
    if (e < Eiu) {
        int d = iu_e[Eiu + e];
        int p = atomicAdd(&cur[d], 1);
        csr_u[p] = iu_e[e];
    } else if (e < Eiu + Eui) {
        int e2 = e - Eiu;
        int d = ui_e[Eui + e2];
        int p = atomicAdd(&cur[NU + d], 1);
        csr_i[p] = ui_e[e2];
    }
}

// x = bf16( tgt + mean(src rows) ), all bf16 reads; one wave per target row.
// 4/2/1 unrolled gather: up to 4 independent row loads in flight.
__global__ void k_msg2(const unsigned short* __restrict__ uf_bf,
                       const unsigned short* __restrict__ if_bf,
                       const int* __restrict__ rs_u, const int* __restrict__ csr_u,
                       const int* __restrict__ rs_i, const int* __restrict__ csr_i,
                       unsigned short* __restrict__ x_u, unsigned short* __restrict__ x_i,
                       int NU, int NI) {
    int wv = (blockIdx.x * blockDim.x + threadIdx.x) >> 6;
    int lane = threadIdx.x & 63;
    if (wv >= NU + NI) return;
    const unsigned short* src; const unsigned short* tgt;
    const int* rs; const int* csr; unsigned short* xo; int w;
    if (wv < NU) { src = if_bf; tgt = uf_bf; rs = rs_u; csr = csr_u; xo = x_u; w = wv; }
    else         { src = uf_bf; tgt = if_bf; rs = rs_i; csr = csr_i; xo = x_i; w = wv - NU; }

    int s0 = rs[w], s1 = rs[w + 1];
    float ax0=0,ay0=0,az0=0,aw0=0, ax1=0,ay1=0,az1=0,aw1=0;
    float ax2=0,ay2=0,az2=0,aw2=0, ax3=0,ay3=0,az3=0,aw3=0;
    int i = s0;
    for (; i + 4 <= s1; i += 4) {
        int e0 = csr[i], e1 = csr[i+1], e2 = csr[i+2], e3 = csr[i+3];
        ushort4 r0 = ((const ushort4*)(src + (size_t)e0 * D))[lane];
        ushort4 r1 = ((const ushort4*)(src + (size_t)e1 * D))[lane];
        ushort4 r2 = ((const ushort4*)(src + (size_t)e2 * D))[lane];
        ushort4 r3 = ((const ushort4*)(src + (size_t)e3 * D))[lane];
        ax0 += bf2f(r0.x); ay0 += bf2f(r0.y); az0 += bf2f(r0.z); aw0 += bf2f(r0.w);
        ax1 += bf2f(r1.x); ay1 += bf2f(r1.y); az1 += bf2f(r1.z); aw1 += bf2f(r1.w);
        ax2 += bf2f(r2.x); ay2 += bf2f(r2.y); az2 += bf2f(r2.z); aw2 += bf2f(r2.w);
        ax3 += bf2f(r3.x); ay3 += bf2f(r3.y); az3 += bf2f(r3.z); aw3 += bf2f(r3.w);
    }
    if (i + 2 <= s1) {
        int e0 = csr[i], e1 = csr[i+1];
        ushort4 r0 = ((const ushort4*)(src + (size_t)e0 * D))[lane];
        ushort4 r1 = ((const ushort4*)(src + (size_t)e1 * D))[lane];
        ax0 += bf2f(r0.x); ay0 += bf2f(r0.y); az0 += bf2f(r0.z); aw0 += bf2f(r0.w);
        ax1 += bf2f(r1.x); ay1 += bf2f(r1.y); az1 += bf2f(r1.z); aw1 += bf2f(r1.w);
        i += 2;
    }
    if (i < s1) {
        int e0 = csr[i];
        ushort4 r0 = ((const ushort4*)(src + (size_t)e0 * D))[lane];
        ax2 += bf2f(r0.x); ay2 += bf2f(r0.y); az2 += bf2f(r0.z); aw2 += bf2f(r0.w);
    }
    float sx = (ax0 + ax1) + (ax2 + ax3);
    float sy = (ay0 + ay1) + (ay2 + ay3);
    float sz = (az0 + az1) + (az2 + az3);
    float sw = (aw0 + aw1) + (aw2 + aw3);
    int cnt = s1 - s0;
    float inv = 1.0f / (float)(cnt > 0 ? cnt : 1);
    ushort4 tv = ((const ushort4*)(tgt + (size_t)w * D))[lane];
    ushort4 o;
    o.x = f2bf(bf2f(tv.x) + sx * inv);
    o.y = f2bf(bf2f(tv.y) + sy * inv);
    o.z = f2bf(bf2f(tv.z) + sz * inv);
    o.w = f2bf(bf2f(tv.w) + sw * inv);
    ((ushort4*)(xo + (size_t)w * D))[lane] = o;
}

// bf16-MFMA GEMM + bias + ReLU + LayerNorm; both sides in one dispatch.
__launch_bounds__(256)
__global__ void k_gemm2(const unsigned short* __restrict__ x_u,
                        const unsigned short* __restrict__ x_i,
                        const unsigned short* __restrict__ Wt_u,
                        const unsigned short* __restrict__ Wt_i,
                        const float* __restrict__ bu, const float* __restrict__ bi,
                        const float* __restrict__ gamma, const float* __restrict__ beta,
                        int NU, int NI, int nbU, float* __restrict__ out) {
    __shared__ __hip_bfloat16 As[BM][LDK];
    __shared__ __hip_bfloat16 Bs[D][LDK];
    __shared__ float red_s[BM][4];
    __shared__ float red_q[BM][4];

    int b = blockIdx.x;
    bool isU = b < nbU;
    const unsigned short* X  = isU ? x_u : x_i;
    const unsigned short* Wt = isU ? Wt_u : Wt_i;
    const float* bias        = isU ? bu : bi;
    float* Y                 = isU ? out : out + (size_t)NU * D;
    int N                    = isU ? NU : NI;
    int row0 = (isU ? b : b - nbU) * BM;

    int t = threadIdx.x;
    int lane = t & 63;
    int w = t >> 6;
    int l15 = lane & 15;
    int l4 = lane >> 4;

    f32x4 acc[4][4];
    f32x4 zero = {0.f, 0.f, 0.f, 0.f};
    #pragma unroll
    for (int fr = 0; fr < 4; fr++)
        #pragma unroll
        for (int fc = 0; fc < 4; fc++)
            acc[fr][fc] = zero;

    for (int k0 = 0; k0 < D; k0 += BK) {
        // stage A: 64 rows x 64 k (bf16 direct)
        {
            int i = t >> 2;
            int kq = (t & 3) * 16;
            int r = row0 + i;
            uint4 b0 = {0,0,0,0}, b1 = {0,0,0,0};
            if (r < N) {
                const uint4* p = (const uint4*)&X[(size_t)r * D + k0 + kq];
                b0 = p[0]; b1 = p[1];
            }
            *(uint4*)&As[i][kq]     = b0;
            *(uint4*)&As[i][kq + 8] = b1;
        }
        // stage B: 256 cols x 64 k from Wt [c][k]
        #pragma unroll
        for (int pass = 0; pass < 4; pass++) {
            int c = pass * 64 + (t >> 2);
            int kq = (t & 3) * 16;
            const uint4* p = (const uint4*)&Wt[(size_t)c * D + k0 + kq];
            uint4 b0 = p[0], b1 = p[1];
            *(uint4*)&Bs[c][kq]     = b0;
            *(uint4*)&Bs[c][kq + 8] = b1;
        }
        __syncthreads();

        #pragma unroll
        for (int ks = 0; ks < 2; ks++) {
            bf16x8 af[4], bg[4];
            #pragma unroll
            for (int fr = 0; fr < 4; fr++)
                af[fr] = *(const bf16x8*)&As[fr * 16 + l15][ks * 32 + l4 * 8];
            #pragma unroll
            for (int fc = 0; fc < 4; fc++)
                bg[fc] = *(const bf16x8*)&Bs[w * 64 + fc * 16 + l15][ks * 32 + l4 * 8];
            #pragma unroll
            for (int fr = 0; fr < 4; fr++)
                #pragma unroll
                for (int fc = 0; fc < 4; fc++)
                    acc[fr][fc] = __builtin_amdgcn_mfma_f32_16x16x32_bf16(
                        af[fr], bg[fc], acc[fr][fc], 0, 0, 0);
        }
        __syncthreads();
    }

    float bias_c[4], gam_c[4], bet_c[4];
    #pragma unroll
    for (int fc = 0; fc < 4; fc++) {
        int col = w * 64 + fc * 16 + l15;
        bias_c[fc] = bias[col];
        gam_c[fc]  = gamma[col];
        bet_c[fc]  = beta[col];
    }

    #pragma unroll
    for (int fr = 0; fr < 4; fr++) {
        #pragma unroll
        for (int r = 0; r < 4; r++) {
            int row = fr * 16 + l4 * 4 + r;
            float s = 0.f, q = 0.f;
            #pragma unroll
            for (int fc = 0; fc < 4; fc++) {
                float v = acc[fr][fc][r] + bias_c[fc];
                v = fmaxf(v, 0.f);
                acc[fr][fc][r] = v;
                s += v;
                q += v * v;
            }
            #pragma unroll
            for (int m = 1; m < 16; m <<= 1) {
                s += __shfl_xor(s, m);
                q += __shfl_xor(q, m);
            }
            if (l15 == 0) { red_s[row][w] = s; red_q[row][w] = q; }
        }
    }
    __syncthreads();

    #pragma unroll
    for (int fr = 0; fr < 4; fr++) {
        #pragma unroll
        for (int r = 0; r < 4; r++) {
            int row = fr * 16 + l4 * 4 + r;
            int grow = row0 + row;
            if (grow >= N) continue;
            float s = red_s[row][0] + red_s[row][1] + red_s[row][2] + red_s[row][3];
            float q = red_q[row][0] + red_q[row][1] + red_q[row][2] + red_q[row][3];
            float mu  = s * (1.0f / 256.0f);
            float var = q * (1.0f / 256.0f) - mu * mu;
            float rstd = rsqrtf(var + 1e-5f);
            #pragma unroll
            for (int fc = 0; fc < 4; fc++) {
                int col = w * 64 + fc * 16 + l15;
                Y[(size_t)grow * D + col] = (acc[fr][fc][r] - mu) * rstd * gam_c[fc] + bet_c[fc];
            }
        }
    }
}

// ======================= FALLBACK PATH (R2, small-ws) =======================

__global__ void k_hist(const int* __restrict__ dst, int E, int* __restrict__ deg) {
    int e = blockIdx.x * blockDim.x + threadIdx.x;
    if (e < E) atomicAdd(&deg[dst[e]], 1);
}

__global__ void k_scan_block(const int* __restrict__ deg, int N,
                             int* __restrict__ rs, int* __restrict__ bsums) {
    __shared__ int s[1024];
    int base = blockIdx.x * 1024;
    int t = threadIdx.x;
    int v = (base + t < N) ? deg[base + t] : 0;
    s[t] = v;
    __syncthreads();
    for (int off = 1; off < 1024; off <<= 1) {
        int add = (t >= off) ? s[t - off] : 0;
        __syncthreads();
        s[t] += add;
        __syncthreads();
    }
    if (base + t < N) rs[base + t + 1] = s[t];
    if (t == 1023) bsums[blockIdx.x] = s[1023];
}

__global__ void k_scan_sums(int* __restrict__ bsums, int nb) {
    __shared__ int s[1024];
    int t = threadIdx.x;
    int v = (t < nb) ? bsums[t] : 0;
    s[t] = v;
    __syncthreads();
    for (int off = 1; off < 1024; off <<= 1) {
        int add = (t >= off) ? s[t - off] : 0;
        __syncthreads();
        s[t] += add;
        __syncthreads();
    }
    if (t < nb) bsums[t] = s[t] - v;
}

__global__ void k_finalize_rs(int N, int* __restrict__ rs, const int* __restrict__ bsums) {
    int i = blockIdx.x * blockDim.x + threadIdx.x;
    if (i < N) rs[i + 1] += bsums[i >> 10];
    if (i == 0) rs[0] = 0;
}

__global__ void k_fill(const int* __restrict__ src, const int* __restrict__ dst, int E,
                       const int* __restrict__ rs, int* __restrict__ cursor,
                       int* __restrict__ csr) {
    int e = blockIdx.x * blockDim.x + threadIdx.x;
    if (e < E) {
        int d = dst[e];
        int p = atomicAdd(&cursor[d], 1);
        csr[rs[d] + p] = src[e];
    }
}

__global__ void k_msg_x(const float* __restrict__ srcf, const float* __restrict__ tgtf,
                        const int* __restrict__ rs, const int* __restrict__ csr,
                        int N, float* __restrict__ xout) {
    int wave = (blockIdx.x * blockDim.x + threadIdx.x) >> 6;
    int lane = threadIdx.x & 63;
    if (wave >= N) return;
    int s0 = rs[wave], s1 = rs[wave + 1];
    float4 acc = make_float4(0.f, 0.f, 0.f, 0.f);
    for (int i = s0; i < s1; i++) {
        int s = csr[i];
        float4 f = *(const float4*)&srcf[(size_t)s * D + lane * 4];
        acc.x += f.x; acc.y += f.y; acc.z += f.z; acc.w += f.w;
    }
    int cnt = s1 - s0;
    float inv = 1.0f / (float)(cnt > 0 ? cnt : 1);
    float4 t = *(const float4*)&tgtf[(size_t)wave * D + lane * 4];
    float4 x;
    x.x = t.x + acc.x * inv;
    x.y = t.y + acc.y * inv;
    x.z = t.z + acc.z * inv;
    x.w = t.w + acc.w * inv;
    *(float4*)&xout[(size_t)wave * D + lane * 4] = x;
}

__global__ void k_wcvt(const float* __restrict__ W0, const float* __restrict__ W1,
                       __hip_bfloat16* __restrict__ Wt0, __hip_bfloat16* __restrict__ Wt1) {
    int b = blockIdx.x;
    const float* W = (b < 256) ? W0 : W1;
    __hip_bfloat16* Wt = (b < 256) ? Wt0 : Wt1;
    int k = b & 255;
    int c = threadIdx.x;
    Wt[(size_t)c * 256 + k] = __float2bfloat16(W[(size_t)k * 256 + c]);
}

__launch_bounds__(256)
__global__ void k_gemm_mfma_ln(const float* __restrict__ X,
                               const __hip_bfloat16* __restrict__ Wt,
                               const float* __restrict__ bias,
                               const float* __restrict__ gamma,
                               const float* __restrict__ beta,
                               int N, float* __restrict__ Y) {
    __shared__ __hip_bfloat16 As[BM][LDK];
    __shared__ __hip_bfloat16 Bs[D][LDK];
    __shared__ float red_s[BM][4];
    __shared__ float red_q[BM][4];

    int t = threadIdx.x;
    int lane = t & 63;
    int w = t >> 6;
    int l15 = lane & 15;
    int l4 = lane >> 4;
    int row0 = blockIdx.x * BM;

    f32x4 acc[4][4];
    f32x4 zero = {0.f, 0.f, 0.f, 0.f};
    #pragma unroll
    for (int fr = 0; fr < 4; fr++)
        #pragma unroll
        for (int fc = 0; fc < 4; fc++)
            acc[fr][fc] = zero;

    for (int k0 = 0; k0 < D; k0 += BK) {
        {
            int i = t >> 2;
            int kq = (t & 3) * 16;
            int r = row0 + i;
            float4 f[4];
            if (r < N) {
                const float4* p = (const float4*)&X[(size_t)r * D + k0 + kq];
                f[0] = p[0]; f[1] = p[1]; f[2] = p[2]; f[3] = p[3];
            } else {
                float4 z4 = make_float4(0.f, 0.f, 0.f, 0.f);
                f[0] = z4; f[1] = z4; f[2] = z4; f[3] = z4;
            }
            __hip_bfloat16 vb[16];
            #pragma unroll
            for (int q = 0; q < 4; q++) {
                vb[q * 4 + 0] = __float2bfloat16(f[q].x);
                vb[q * 4 + 1] = __float2bfloat16(f[q].y);
                vb[q * 4 + 2] = __float2bfloat16(f[q].z);
                vb[q * 4 + 3] = __float2bfloat16(f[q].w);
            }
            *(uint4*)&As[i][kq]     = *(uint4*)&vb[0];
            *(uint4*)&As[i][kq + 8] = *(uint4*)&vb[8];
        }
        #pragma unroll
        for (int pass = 0; pass < 4; pass++) {
            int c = pass * 64 + (t >> 2);
            int kq = (t & 3) * 16;
            const uint4* p = (const uint4*)&Wt[(size_t)c * D + k0 + kq];
            uint4 b0 = p[0], b1 = p[1];
            *(uint4*)&Bs[c][kq]     = b0;
            *(uint4*)&Bs[c][kq + 8] = b1;
        }
        __syncthreads();

        #pragma unroll
        for (int ks = 0; ks < 2; ks++) {
            bf16x8 af[4], bg[4];
            #pragma unroll
            for (int fr = 0; fr < 4; fr++)
                af[fr] = *(const bf16x8*)&As[fr * 16 + l15][ks * 32 + l4 * 8];
            #pragma unroll
            for (int fc = 0; fc < 4; fc++)
                bg[fc] = *(const bf16x8*)&Bs[w * 64 + fc * 16 + l15][ks * 32 + l4 * 8];
            #pragma unroll
            for (int fr = 0; fr < 4; fr++)
                #pragma unroll
                for (int fc = 0; fc < 4; fc++)
                    acc[fr][fc] = __builtin_amdgcn_mfma_f32_16x16x32_bf16(
                        af[fr], bg[fc], acc[fr][fc], 0, 0, 0);
        }
        __syncthreads();
    }

    float bias_c[4], gam_c[4], bet_c[4];
    #pragma unroll
    for (int fc = 0; fc < 4; fc++) {
        int col = w * 64 + fc * 16 + l15;
        bias_c[fc] = bias[col];
        gam_c[fc]  = gamma[col];
        bet_c[fc]  = beta[col];
    }

    #pragma unroll
    for (int fr = 0; fr < 4; fr++) {
        #pragma unroll
        for (int r = 0; r < 4; r++) {
            int row = fr * 16 + l4 * 4 + r;
            float s = 0.f, q = 0.f;
            #pragma unroll
            for (int fc = 0; fc < 4; fc++) {
                float v = acc[fr][fc][r] + bias_c[fc];
                v = fmaxf(v, 0.f);
                acc[fr][fc][r] = v;
                s += v;
                q += v * v;
            }
            #pragma unroll
            for (int m = 1; m < 16; m <<= 1) {
                s += __shfl_xor(s, m);
                q += __shfl_xor(q, m);
            }
            if (l15 == 0) { red_s[row][w] = s; red_q[row][w] = q; }
        }
    }
    __syncthreads();

    #pragma unroll
    for (int fr = 0; fr < 4; fr++) {
        #pragma unroll
        for (int r = 0; r < 4; r++) {
            int row = fr * 16 + l4 * 4 + r;
            int grow = row0 + row;
            if (grow >= N) continue;
            float s = red_s[row][0] + red_s[row][1] + red_s[row][2] + red_s[row][3];
            float q = red_q[row][0] + red_q[row][1] + red_q[row][2] + red_q[row][3];
            float mu  = s * (1.0f / 256.0f);
            float var = q * (1.0f / 256.0f) - mu * mu;
            float rstd = rsqrtf(var + 1e-5f);
            #pragma unroll
            for (int fc = 0; fc < 4; fc++) {
                int col = w * 64 + fc * 16 + l15;
                Y[(size_t)grow * D + col] = (acc[fr][fc][r] - mu) * rstd * gam_c[fc] + bet_c[fc];
            }
        }
    }
}

// ======================= launch =======================

extern "C" void kernel_launch(void* const* d_in, const int* in_sizes, int n_in,
                              void* d_out, int out_size, void* d_ws, size_t ws_size,
                              hipStream_t stream) {
    const float* uf    = (const float*)d_in[0];
    const float* itf   = (const float*)d_in[1];
    const int*   ui_e  = (const int*)d_in[2];   // [2, Eui] user->item
    const int*   iu_e  = (const int*)d_in[3];   // [2, Eiu] item->user
    const float* Wu    = (const float*)d_in[4];
    const float* bu    = (const float*)d_in[5];
    const float* Wi    = (const float*)d_in[6];
    const float* bi    = (const float*)d_in[7];
    const float* gamma = (const float*)d_in[8];
    const float* beta  = (const float*)d_in[9];

    int NU  = in_sizes[0] / D;
    int NI  = in_sizes[1] / D;
    int Eui = in_sizes[2] / 2;
    int Eiu = in_sizes[3] / 2;
    int Nmax = NU > NI ? NU : NI;

    float* out   = (float*)d_out;
    size_t nfU = (size_t)NU * D;
    size_t nfI = (size_t)NI * D;
    size_t nfTot = nfU + nfI;

    // fast-path ws layout
    unsigned short* uf_bf = (unsigned short*)d_ws;     // nfU
    unsigned short* if_bf = uf_bf + nfU;               // nfI
    unsigned short* x_u   = if_bf + nfI;               // nfU
    unsigned short* x_i   = x_u + nfU;                 // nfI
    unsigned short* Wt_u2 = x_i + nfI;                 // 65536
    unsigned short* Wt_i2 = Wt_u2 + 65536;             // 65536
    int* deg2  = (int*)(Wt_i2 + 65536);                // NU+NI
    int* rs_u  = deg2 + (NU + NI);                     // NU+1
    int* rs_i  = rs_u + (NU + 1);                      // NI+1
    int* cur2  = rs_i + (NI + 1);                      // NU+NI
    int* csr_u = cur2 + (NU + NI);                     // Eiu
    int* csr_i = csr_u + Eiu;                          // Eui
    size_t needed = (size_t)((char*)(csr_i + Eui) - (char*)d_ws);

    if (ws_size >= needed) {
        int nbF = (int)((nfTot + 2047) / 2048);
        k_cvt_all<<<nbF + 512, 256, 0, stream>>>(uf, itf, Wu, Wi, uf_bf, Wt_u2, Wt_i2,
                                                 nfU, nfTot, nbF);
        hipMemsetAsync(deg2, 0, (size_t)(NU + NI) * sizeof(int), stream);
        int Etot = Eiu + Eui;
        k_hist2<<<(Etot + 255) / 256, 256, 0, stream>>>(iu_e, Eiu, ui_e, Eui, deg2, NU);
        k_scan2<<<2, 1024, 0, stream>>>(deg2, rs_u, rs_i, cur2, NU, NI);
        k_fill2<<<(Etot + 255) / 256, 256, 0, stream>>>(iu_e, Eiu, ui_e, Eui, cur2, NU,
                                                        csr_u, csr_i);
        int wvTot = NU + NI;
        k_msg2<<<(wvTot + 3) / 4, 256, 0, stream>>>(uf_bf, if_bf, rs_u, csr_u, rs_i, csr_i,
                                                    x_u, x_i, NU, NI);
        int nbU = (NU + BM - 1) / BM;
        int nbI = (NI + BM - 1) / BM;
        k_gemm2<<<nbU + nbI, 256, 0, stream>>>(x_u, x_i, Wt_u2, Wt_i2, bu, bi, gamma, beta,
                                               NU, NI, nbU, out);
        return;
    }

    // ---------- fallback: R2 path (needs ~2.2 MB ws) ----------
    float* u_out = out;
    float* i_out = out + nfU;
    __hip_bfloat16* Wt_u = (__hip_bfloat16*)d_ws;
    __hip_bfloat16* Wt_i = Wt_u + 256 * 256;
    int* deg    = (int*)(Wt_i + 256 * 256);
    int* rs     = deg + Nmax;
    int* bsums  = rs + Nmax + 1;
    int* cursor = bsums + 1024;
    int* csr    = cursor + Nmax;

    k_wcvt<<<512, 256, 0, stream>>>(Wu, Wi, Wt_u, Wt_i);

    auto run_side = [&](const float* srcf, const float* tgtf, const int* edges, int E,
                        int N, const __hip_bfloat16* Wt, const float* bias, float* y) {
        const int* esrc = edges;
        const int* edst = edges + E;
        hipMemsetAsync(deg, 0, (size_t)N * sizeof(int), stream);
        hipMemsetAsync(cursor, 0, (size_t)N * sizeof(int), stream);
        k_hist<<<(E + 255) / 256, 256, 0, stream>>>(edst, E, deg);
        int nb = (N + 1023) / 1024;
        k_scan_block<<<nb, 1024, 0, stream>>>(deg, N, rs, bsums);
        k_scan_sums<<<1, 1024, 0, stream>>>(bsums, nb);
        k_finalize_rs<<<(N + 255) / 256, 256, 0, stream>>>(N, rs, bsums);
        k_fill<<<(E + 255) / 256, 256, 0, stream>>>(esrc, edst, E, rs, cursor, csr);
        k_msg_x<<<(N + 3) / 4, 256, 0, stream>>>(srcf, tgtf, rs, csr, N, y);
        k_gemm_mfma_ln<<<(N + BM - 1) / BM, 256, 0, stream>>>(y, Wt, bias, gamma, beta, N, y);
    };

    run_side(itf, uf, iu_e, Eiu, NU, Wt_u, bu, u_out);
    run_side(uf, itf, ui_e, Eui, NI, Wt_i, bi, i_out);
}

// Round 4
// 220.168 us; speedup vs baseline: 1.4421x; 1.4421x over previous
//
#include <hip/hip_runtime.h>
#include <hip/hip_bf16.h>

#define D 256
#define BM 64
#define BK 64
#define LDK 72   // padded LDS k-stride (144B rows: 16B-aligned, 2-way bank alias = free)

typedef __attribute__((ext_vector_type(8))) __bf16 bf16x8;
typedef __attribute__((ext_vector_type(4))) float f32x4;

__device__ __forceinline__ float bf2f(unsigned short u) {
    union { unsigned int i; float f; } c; c.i = ((unsigned int)u) << 16; return c.f;
}
__device__ __forceinline__ unsigned short f2bf(float f) {
    __hip_bfloat16 h = __float2bfloat16(f);
    return *reinterpret_cast<unsigned short*>(&h);
}

// ======================= FAST PATH (fused, bf16 data path, unified CSR) ==============

// convert features fp32->bf16 (blocks [0,nbF)) and W -> Wt[c][k] bf16 (blocks [nbF,nbF+512))
__global__ void k_cvt_all(const float* __restrict__ uf, const float* __restrict__ itf,
                          const float* __restrict__ Wu, const float* __restrict__ Wi,
                          unsigned short* __restrict__ feat_bf,
                          unsigned short* __restrict__ Wt_u, unsigned short* __restrict__ Wt_i,
                          size_t nfU, size_t nfTot, int nbF) {
    int b = blockIdx.x;
    if (b < nbF) {
        size_t base = ((size_t)b * 256 + threadIdx.x) * 8;
        if (base < nfTot) {
            const float* s = (base < nfU) ? (uf + base) : (itf + (base - nfU));
            float4 f0 = *(const float4*)s;
            float4 f1 = *(const float4*)(s + 4);
            ushort4 o0, o1;
            o0.x = f2bf(f0.x); o0.y = f2bf(f0.y); o0.z = f2bf(f0.z); o0.w = f2bf(f0.w);
            o1.x = f2bf(f1.x); o1.y = f2bf(f1.y); o1.z = f2bf(f1.z); o1.w = f2bf(f1.w);
            ((ushort4*)(feat_bf + base))[0] = o0;
            ((ushort4*)(feat_bf + base))[1] = o1;
        }
    } else {
        int b2 = b - nbF;
        const float* W = (b2 < 256) ? Wu : Wi;
        unsigned short* Wt = (b2 < 256) ? Wt_u : Wt_i;
        int k = b2 & 255;
        int c = threadIdx.x;
        Wt[(size_t)c * 256 + k] = f2bf(W[(size_t)k * 256 + c]);
    }
}

// degree histogram for both sides in one dispatch (unified deg[NU+NI])
__global__ void k_hist2(const int* __restrict__ iu_e, int Eiu,
                        const int* __restrict__ ui_e, int Eui,
                        int* __restrict__ deg, int NU) {
    int e = blockIdx.x * blockDim.x + threadIdx.x;
    if (e < Eiu) {
        atomicAdd(&deg[iu_e[Eiu + e]], 1);
    } else if (e < Eiu + Eui) {
        int e2 = e - Eiu;
        atomicAdd(&deg[NU + ui_e[Eui + e2]], 1);
    }
}

// per-1024-block inclusive scan of deg -> rs[i+1]; block totals -> bsums
__global__ void k_scan_block(const int* __restrict__ deg, int N,
                             int* __restrict__ rs, int* __restrict__ bsums) {
    __shared__ int s[1024];
    int base = blockIdx.x * 1024;
    int t = threadIdx.x;
    int v = (base + t < N) ? deg[base + t] : 0;
    s[t] = v;
    __syncthreads();
    for (int off = 1; off < 1024; off <<= 1) {
        int add = (t >= off) ? s[t - off] : 0;
        __syncthreads();
        s[t] += add;
        __syncthreads();
    }
    if (base + t < N) rs[base + t + 1] = s[t];
    if (t == 1023) bsums[blockIdx.x] = s[1023];
}

// exclusive scan of block sums (nb <= 1024)
__global__ void k_scan_sums(int* __restrict__ bsums, int nb) {
    __shared__ int s[1024];
    int t = threadIdx.x;
    int v = (t < nb) ? bsums[t] : 0;
    s[t] = v;
    __syncthreads();
    for (int off = 1; off < 1024; off <<= 1) {
        int add = (t >= off) ? s[t - off] : 0;
        __syncthreads();
        s[t] += add;
        __syncthreads();
    }
    if (t < nb) bsums[t] = s[t] - v;
}

// finalize rs and cursor: each thread i owns slots rs[i+1], cur[i+1]; no races.
__global__ void k_finalize(int N, int* __restrict__ rs, int* __restrict__ cur,
                           const int* __restrict__ bsums) {
    int i = blockIdx.x * blockDim.x + threadIdx.x;
    if (i < N) {
        int v = rs[i + 1] + bsums[i >> 10];
        rs[i + 1] = v;
        cur[i + 1] = v;
    }
    if (i == 0) { rs[0] = 0; cur[0] = 0; }
}

// fill unified csr: user targets land in [0,Eiu), item targets in [Eiu,Etot)
__global__ void k_fill2(const int* __restrict__ iu_e, int Eiu,
                        const int* __restrict__ ui_e, int Eui,
                        int* __restrict__ cur, int NU,
                        int* __restrict__ csr) {
    int e = blockIdx.x * blockDim.x + threadIdx.x;
    if (e < Eiu) {
        int d = iu_e[Eiu + e];
        int p = atomicAdd(&cur[d], 1);
        csr[p] = iu_e[e];
    } else if (e < Eiu + Eui) {
        int e2 = e - Eiu;
        int d = ui_e[Eui + e2];
        int p = atomicAdd(&cur[NU + d], 1);
        csr[p] = ui_e[e2];
    }
}

// x = bf16( tgt + mean(src rows) ), all bf16; one wave per target row, unified rs/csr.
__global__ void k_msg2(const unsigned short* __restrict__ uf_bf,
                       const unsigned short* __restrict__ if_bf,
                       const int* __restrict__ rs, const int* __restrict__ csr,
                       unsigned short* __restrict__ x_u, unsigned short* __restrict__ x_i,
                       int NU, int NI) {
    int wv = (blockIdx.x * blockDim.x + threadIdx.x) >> 6;
    int lane = threadIdx.x & 63;
    if (wv >= NU + NI) return;
    const unsigned short* src; const unsigned short* tgt; unsigned short* xo; int w;
    if (wv < NU) { src = if_bf; tgt = uf_bf; xo = x_u; w = wv; }
    else         { src = uf_bf; tgt = if_bf; xo = x_i; w = wv - NU; }

    int s0 = rs[wv], s1 = rs[wv + 1];
    float ax0=0,ay0=0,az0=0,aw0=0, ax1=0,ay1=0,az1=0,aw1=0;
    float ax2=0,ay2=0,az2=0,aw2=0, ax3=0,ay3=0,az3=0,aw3=0;
    int i = s0;
    for (; i + 4 <= s1; i += 4) {
        int e0 = csr[i], e1 = csr[i+1], e2 = csr[i+2], e3 = csr[i+3];
        ushort4 r0 = ((const ushort4*)(src + (size_t)e0 * D))[lane];
        ushort4 r1 = ((const ushort4*)(src + (size_t)e1 * D))[lane];
        ushort4 r2 = ((const ushort4*)(src + (size_t)e2 * D))[lane];
        ushort4 r3 = ((const ushort4*)(src + (size_t)e3 * D))[lane];
        ax0 += bf2f(r0.x); ay0 += bf2f(r0.y); az0 += bf2f(r0.z); aw0 += bf2f(r0.w);
        ax1 += bf2f(r1.x); ay1 += bf2f(r1.y); az1 += bf2f(r1.z); aw1 += bf2f(r1.w);
        ax2 += bf2f(r2.x); ay2 += bf2f(r2.y); az2 += bf2f(r2.z); aw2 += bf2f(r2.w);
        ax3 += bf2f(r3.x); ay3 += bf2f(r3.y); az3 += bf2f(r3.z); aw3 += bf2f(r3.w);
    }
    if (i + 2 <= s1) {
        int e0 = csr[i], e1 = csr[i+1];
        ushort4 r0 = ((const ushort4*)(src + (size_t)e0 * D))[lane];
        ushort4 r1 = ((const ushort4*)(src + (size_t)e1 * D))[lane];
        ax0 += bf2f(r0.x); ay0 += bf2f(r0.y); az0 += bf2f(r0.z); aw0 += bf2f(r0.w);
        ax1 += bf2f(r1.x); ay1 += bf2f(r1.y); az1 += bf2f(r1.z); aw1 += bf2f(r1.w);
        i += 2;
    }
    if (i < s1) {
        int e0 = csr[i];
        ushort4 r0 = ((const ushort4*)(src + (size_t)e0 * D))[lane];
        ax2 += bf2f(r0.x); ay2 += bf2f(r0.y); az2 += bf2f(r0.z); aw2 += bf2f(r0.w);
    }
    float sx = (ax0 + ax1) + (ax2 + ax3);
    float sy = (ay0 + ay1) + (ay2 + ay3);
    float sz = (az0 + az1) + (az2 + az3);
    float sw = (aw0 + aw1) + (aw2 + aw3);
    int cnt = s1 - s0;
    float inv = 1.0f / (float)(cnt > 0 ? cnt : 1);
    ushort4 tv = ((const ushort4*)(tgt + (size_t)w * D))[lane];
    ushort4 o;
    o.x = f2bf(bf2f(tv.x) + sx * inv);
    o.y = f2bf(bf2f(tv.y) + sy * inv);
    o.z = f2bf(bf2f(tv.z) + sz * inv);
    o.w = f2bf(bf2f(tv.w) + sw * inv);
    ((ushort4*)(xo + (size_t)w * D))[lane] = o;
}

// bf16-MFMA GEMM + bias + ReLU + LayerNorm; both sides in one dispatch.
__launch_bounds__(256)
__global__ void k_gemm2(const unsigned short* __restrict__ x_u,
                        const unsigned short* __restrict__ x_i,
                        const unsigned short* __restrict__ Wt_u,
                        const unsigned short* __restrict__ Wt_i,
                        const float* __restrict__ bu, const float* __restrict__ bi,
                        const float* __restrict__ gamma, const float* __restrict__ beta,
                        int NU, int NI, int nbU, float* __restrict__ out) {
    __shared__ __hip_bfloat16 As[BM][LDK];
    __shared__ __hip_bfloat16 Bs[D][LDK];
    __shared__ float red_s[BM][4];
    __shared__ float red_q[BM][4];

    int b = blockIdx.x;
    bool isU = b < nbU;
    const unsigned short* X  = isU ? x_u : x_i;
    const unsigned short* Wt = isU ? Wt_u : Wt_i;
    const float* bias        = isU ? bu : bi;
    float* Y                 = isU ? out : out + (size_t)NU * D;
    int N                    = isU ? NU : NI;
    int row0 = (isU ? b : b - nbU) * BM;

    int t = threadIdx.x;
    int lane = t & 63;
    int w = t >> 6;
    int l15 = lane & 15;
    int l4 = lane >> 4;

    f32x4 acc[4][4];
    f32x4 zero = {0.f, 0.f, 0.f, 0.f};
    #pragma unroll
    for (int fr = 0; fr < 4; fr++)
        #pragma unroll
        for (int fc = 0; fc < 4; fc++)
            acc[fr][fc] = zero;

    for (int k0 = 0; k0 < D; k0 += BK) {
        // stage A: 64 rows x 64 k (bf16 direct)
        {
            int i = t >> 2;
            int kq = (t & 3) * 16;
            int r = row0 + i;
            uint4 b0 = {0,0,0,0}, b1 = {0,0,0,0};
            if (r < N) {
                const uint4* p = (const uint4*)&X[(size_t)r * D + k0 + kq];
                b0 = p[0]; b1 = p[1];
            }
            *(uint4*)&As[i][kq]     = b0;
            *(uint4*)&As[i][kq + 8] = b1;
        }
        // stage B: 256 cols x 64 k from Wt [c][k]
        #pragma unroll
        for (int pass = 0; pass < 4; pass++) {
            int c = pass * 64 + (t >> 2);
            int kq = (t & 3) * 16;
            const uint4* p = (const uint4*)&Wt[(size_t)c * D + k0 + kq];
            uint4 b0 = p[0], b1 = p[1];
            *(uint4*)&Bs[c][kq]     = b0;
            *(uint4*)&Bs[c][kq + 8] = b1;
        }
        __syncthreads();

        #pragma unroll
        for (int ks = 0; ks < 2; ks++) {
            bf16x8 af[4], bg[4];
            #pragma unroll
            for (int fr = 0; fr < 4; fr++)
                af[fr] = *(const bf16x8*)&As[fr * 16 + l15][ks * 32 + l4 * 8];
            #pragma unroll
            for (int fc = 0; fc < 4; fc++)
                bg[fc] = *(const bf16x8*)&Bs[w * 64 + fc * 16 + l15][ks * 32 + l4 * 8];
            #pragma unroll
            for (int fr = 0; fr < 4; fr++)
                #pragma unroll
                for (int fc = 0; fc < 4; fc++)
                    acc[fr][fc] = __builtin_amdgcn_mfma_f32_16x16x32_bf16(
                        af[fr], bg[fc], acc[fr][fc], 0, 0, 0);
        }
        __syncthreads();
    }

    float bias_c[4], gam_c[4], bet_c[4];
    #pragma unroll
    for (int fc = 0; fc < 4; fc++) {
        int col = w * 64 + fc * 16 + l15;
        bias_c[fc] = bias[col];
        gam_c[fc]  = gamma[col];
        bet_c[fc]  = beta[col];
    }

    #pragma unroll
    for (int fr = 0; fr < 4; fr++) {
        #pragma unroll
        for (int r = 0; r < 4; r++) {
            int row = fr * 16 + l4 * 4 + r;
            float s = 0.f, q = 0.f;
            #pragma unroll
            for (int fc = 0; fc < 4; fc++) {
                float v = acc[fr][fc][r] + bias_c[fc];
                v = fmaxf(v, 0.f);
                acc[fr][fc][r] = v;
                s += v;
                q += v * v;
            }
            #pragma unroll
            for (int m = 1; m < 16; m <<= 1) {
                s += __shfl_xor(s, m);
                q += __shfl_xor(q, m);
            }
            if (l15 == 0) { red_s[row][w] = s; red_q[row][w] = q; }
        }
    }
    __syncthreads();

    #pragma unroll
    for (int fr = 0; fr < 4; fr++) {
        #pragma unroll
        for (int r = 0; r < 4; r++) {
            int row = fr * 16 + l4 * 4 + r;
            int grow = row0 + row;
            if (grow >= N) continue;
            float s = red_s[row][0] + red_s[row][1] + red_s[row][2] + red_s[row][3];
            float q = red_q[row][0] + red_q[row][1] + red_q[row][2] + red_q[row][3];
            float mu  = s * (1.0f / 256.0f);
            float var = q * (1.0f / 256.0f) - mu * mu;
            float rstd = rsqrtf(var + 1e-5f);
            #pragma unroll
            for (int fc = 0; fc < 4; fc++) {
                int col = w * 64 + fc * 16 + l15;
                Y[(size_t)grow * D + col] = (acc[fr][fc][r] - mu) * rstd * gam_c[fc] + bet_c[fc];
            }
        }
    }
}

// ======================= FALLBACK PATH (R2, small-ws) =======================

__global__ void k_hist(const int* __restrict__ dst, int E, int* __restrict__ deg) {
    int e = blockIdx.x * blockDim.x + threadIdx.x;
    if (e < E) atomicAdd(&deg[dst[e]], 1);
}

__global__ void k_finalize_rs(int N, int* __restrict__ rs, const int* __restrict__ bsums) {
    int i = blockIdx.x * blockDim.x + threadIdx.x;
    if (i < N) rs[i + 1] += bsums[i >> 10];
    if (i == 0) rs[0] = 0;
}

__global__ void k_fill(const int* __restrict__ src, const int* __restrict__ dst, int E,
                       const int* __restrict__ rs, int* __restrict__ cursor,
                       int* __restrict__ csr) {
    int e = blockIdx.x * blockDim.x + threadIdx.x;
    if (e < E) {
        int d = dst[e];
        int p = atomicAdd(&cursor[d], 1);
        csr[rs[d] + p] = src[e];
    }
}

__global__ void k_msg_x(const float* __restrict__ srcf, const float* __restrict__ tgtf,
                        const int* __restrict__ rs, const int* __restrict__ csr,
                        int N, float* __restrict__ xout) {
    int wave = (blockIdx.x * blockDim.x + threadIdx.x) >> 6;
    int lane = threadIdx.x & 63;
    if (wave >= N) return;
    int s0 = rs[wave], s1 = rs[wave + 1];
    float4 acc = make_float4(0.f, 0.f, 0.f, 0.f);
    for (int i = s0; i < s1; i++) {
        int s = csr[i];
        float4 f = *(const float4*)&srcf[(size_t)s * D + lane * 4];
        acc.x += f.x; acc.y += f.y; acc.z += f.z; acc.w += f.w;
    }
    int cnt = s1 - s0;
    float inv = 1.0f / (float)(cnt > 0 ? cnt : 1);
    float4 t = *(const float4*)&tgtf[(size_t)wave * D + lane * 4];
    float4 x;
    x.x = t.x + acc.x * inv;
    x.y = t.y + acc.y * inv;
    x.z = t.z + acc.z * inv;
    x.w = t.w + acc.w * inv;
    *(float4*)&xout[(size_t)wave * D + lane * 4] = x;
}

__global__ void k_wcvt(const float* __restrict__ W0, const float* __restrict__ W1,
                       __hip_bfloat16* __restrict__ Wt0, __hip_bfloat16* __restrict__ Wt1) {
    int b = blockIdx.x;
    const float* W = (b < 256) ? W0 : W1;
    __hip_bfloat16* Wt = (b < 256) ? Wt0 : Wt1;
    int k = b & 255;
    int c = threadIdx.x;
    Wt[(size_t)c * 256 + k] = __float2bfloat16(W[(size_t)k * 256 + c]);
}

__launch_bounds__(256)
__global__ void k_gemm_mfma_ln(const float* __restrict__ X,
                               const __hip_bfloat16* __restrict__ Wt,
                               const float* __restrict__ bias,
                               const float* __restrict__ gamma,
                               const float* __restrict__ beta,
                               int N, float* __restrict__ Y) {
    __shared__ __hip_bfloat16 As[BM][LDK];
    __shared__ __hip_bfloat16 Bs[D][LDK];
    __shared__ float red_s[BM][4];
    __shared__ float red_q[BM][4];

    int t = threadIdx.x;
    int lane = t & 63;
    int w = t >> 6;
    int l15 = lane & 15;
    int l4 = lane >> 4;
    int row0 = blockIdx.x * BM;

    f32x4 acc[4][4];
    f32x4 zero = {0.f, 0.f, 0.f, 0.f};
    #pragma unroll
    for (int fr = 0; fr < 4; fr++)
        #pragma unroll
        for (int fc = 0; fc < 4; fc++)
            acc[fr][fc] = zero;

    for (int k0 = 0; k0 < D; k0 += BK) {
        {
            int i = t >> 2;
            int kq = (t & 3) * 16;
            int r = row0 + i;
            float4 f[4];
            if (r < N) {
                const float4* p = (const float4*)&X[(size_t)r * D + k0 + kq];
                f[0] = p[0]; f[1] = p[1]; f[2] = p[2]; f[3] = p[3];
            } else {
                float4 z4 = make_float4(0.f, 0.f, 0.f, 0.f);
                f[0] = z4; f[1] = z4; f[2] = z4; f[3] = z4;
            }
            __hip_bfloat16 vb[16];
            #pragma unroll
            for (int q = 0; q < 4; q++) {
                vb[q * 4 + 0] = __float2bfloat16(f[q].x);
                vb[q * 4 + 1] = __float2bfloat16(f[q].y);
                vb[q * 4 + 2] = __float2bfloat16(f[q].z);
                vb[q * 4 + 3] = __float2bfloat16(f[q].w);
            }
            *(uint4*)&As[i][kq]     = *(uint4*)&vb[0];
            *(uint4*)&As[i][kq + 8] = *(uint4*)&vb[8];
        }
        #pragma unroll
        for (int pass = 0; pass < 4; pass++) {
            int c = pass * 64 + (t >> 2);
            int kq = (t & 3) * 16;
            const uint4* p = (const uint4*)&Wt[(size_t)c * D + k0 + kq];
            uint4 b0 = p[0], b1 = p[1];
            *(uint4*)&Bs[c][kq]     = b0;
            *(uint4*)&Bs[c][kq + 8] = b1;
        }
        __syncthreads();

        #pragma unroll
        for (int ks = 0; ks < 2; ks++) {
            bf16x8 af[4], bg[4];
            #pragma unroll
            for (int fr = 0; fr < 4; fr++)
                af[fr] = *(const bf16x8*)&As[fr * 16 + l15][ks * 32 + l4 * 8];
            #pragma unroll
            for (int fc = 0; fc < 4; fc++)
                bg[fc] = *(const bf16x8*)&Bs[w * 64 + fc * 16 + l15][ks * 32 + l4 * 8];
            #pragma unroll
            for (int fr = 0; fr < 4; fr++)
                #pragma unroll
                for (int fc = 0; fc < 4; fc++)
                    acc[fr][fc] = __builtin_amdgcn_mfma_f32_16x16x32_bf16(
                        af[fr], bg[fc], acc[fr][fc], 0, 0, 0);
        }
        __syncthreads();
    }

    float bias_c[4], gam_c[4], bet_c[4];
    #pragma unroll
    for (int fc = 0; fc < 4; fc++) {
        int col = w * 64 + fc * 16 + l15;
        bias_c[fc] = bias[col];
        gam_c[fc]  = gamma[col];
        bet_c[fc]  = beta[col];
    }

    #pragma unroll
    for (int fr = 0; fr < 4; fr++) {
        #pragma unroll
        for (int r = 0; r < 4; r++) {
            int row = fr * 16 + l4 * 4 + r;
            float s = 0.f, q = 0.f;
            #pragma unroll
            for (int fc = 0; fc < 4; fc++) {
                float v = acc[fr][fc][r] + bias_c[fc];
                v = fmaxf(v, 0.f);
                acc[fr][fc][r] = v;
                s += v;
                q += v * v;
            }
            #pragma unroll
            for (int m = 1; m < 16; m <<= 1) {
                s += __shfl_xor(s, m);
                q += __shfl_xor(q, m);
            }
            if (l15 == 0) { red_s[row][w] = s; red_q[row][w] = q; }
        }
    }
    __syncthreads();

    #pragma unroll
    for (int fr = 0; fr < 4; fr++) {
        #pragma unroll
        for (int r = 0; r < 4; r++) {
            int row = fr * 16 + l4 * 4 + r;
            int grow = row0 + row;
            if (grow >= N) continue;
            float s = red_s[row][0] + red_s[row][1] + red_s[row][2] + red_s[row][3];
            float q = red_q[row][0] + red_q[row][1] + red_q[row][2] + red_q[row][3];
            float mu  = s * (1.0f / 256.0f);
            float var = q * (1.0f / 256.0f) - mu * mu;
            float rstd = rsqrtf(var + 1e-5f);
            #pragma unroll
            for (int fc = 0; fc < 4; fc++) {
                int col = w * 64 + fc * 16 + l15;
                Y[(size_t)grow * D + col] = (acc[fr][fc][r] - mu) * rstd * gam_c[fc] + bet_c[fc];
            }
        }
    }
}

// ======================= launch =======================

extern "C" void kernel_launch(void* const* d_in, const int* in_sizes, int n_in,
                              void* d_out, int out_size, void* d_ws, size_t ws_size,
                              hipStream_t stream) {
    const float* uf    = (const float*)d_in[0];
    const float* itf   = (const float*)d_in[1];
    const int*   ui_e  = (const int*)d_in[2];   // [2, Eui] user->item
    const int*   iu_e  = (const int*)d_in[3];   // [2, Eiu] item->user
    const float* Wu    = (const float*)d_in[4];
    const float* bu    = (const float*)d_in[5];
    const float* Wi    = (const float*)d_in[6];
    const float* bi    = (const float*)d_in[7];
    const float* gamma = (const float*)d_in[8];
    const float* beta  = (const float*)d_in[9];

    int NU  = in_sizes[0] / D;
    int NI  = in_sizes[1] / D;
    int Eui = in_sizes[2] / 2;
    int Eiu = in_sizes[3] / 2;
    int Nmax = NU > NI ? NU : NI;
    int Ntot = NU + NI;
    int Etot = Eiu + Eui;

    float* out   = (float*)d_out;
    size_t nfU = (size_t)NU * D;
    size_t nfI = (size_t)NI * D;
    size_t nfTot = nfU + nfI;

    // fast-path ws layout
    unsigned short* uf_bf = (unsigned short*)d_ws;     // nfU
    unsigned short* if_bf = uf_bf + nfU;               // nfI
    unsigned short* x_u   = if_bf + nfI;               // nfU
    unsigned short* x_i   = x_u + nfU;                 // nfI
    unsigned short* Wt_u2 = x_i + nfI;                 // 65536
    unsigned short* Wt_i2 = Wt_u2 + 65536;             // 65536
    int* deg2  = (int*)(Wt_i2 + 65536);                // Ntot
    int* rs2   = deg2 + Ntot;                          // Ntot+1
    int* cur2  = rs2 + Ntot + 1;                       // Ntot+1
    int* bsums = cur2 + Ntot + 1;                      // 1024
    int* csr2  = bsums + 1024;                         // Etot
    size_t needed = (size_t)((char*)(csr2 + Etot) - (char*)d_ws);

    if (ws_size >= needed) {
        int nbF = (int)((nfTot + 2047) / 2048);
        k_cvt_all<<<nbF + 512, 256, 0, stream>>>(uf, itf, Wu, Wi, uf_bf, Wt_u2, Wt_i2,
                                                 nfU, nfTot, nbF);
        hipMemsetAsync(deg2, 0, (size_t)Ntot * sizeof(int), stream);
        k_hist2<<<(Etot + 255) / 256, 256, 0, stream>>>(iu_e, Eiu, ui_e, Eui, deg2, NU);
        int nb = (Ntot + 1023) / 1024;
        k_scan_block<<<nb, 1024, 0, stream>>>(deg2, Ntot, rs2, bsums);
        k_scan_sums<<<1, 1024, 0, stream>>>(bsums, nb);
        k_finalize<<<(Ntot + 255) / 256, 256, 0, stream>>>(Ntot, rs2, cur2, bsums);
        k_fill2<<<(Etot + 255) / 256, 256, 0, stream>>>(iu_e, Eiu, ui_e, Eui, cur2, NU, csr2);
        k_msg2<<<(Ntot + 3) / 4, 256, 0, stream>>>(uf_bf, if_bf, rs2, csr2, x_u, x_i, NU, NI);
        int nbU = (NU + BM - 1) / BM;
        int nbI = (NI + BM - 1) / BM;
        k_gemm2<<<nbU + nbI, 256, 0, stream>>>(x_u, x_i, Wt_u2, Wt_i2, bu, bi, gamma, beta,
                                               NU, NI, nbU, out);
        return;
    }

    // ---------- fallback: R2 path (needs ~2.2 MB ws) ----------
    float* u_out = out;
    float* i_out = out + nfU;
    __hip_bfloat16* Wt_u = (__hip_bfloat16*)d_ws;
    __hip_bfloat16* Wt_i = Wt_u + 256 * 256;
    int* deg    = (int*)(Wt_i + 256 * 256);
    int* rs     = deg + Nmax;
    int* bs     = rs + Nmax + 1;
    int* cursor = bs + 1024;
    int* csr    = cursor + Nmax;

    k_wcvt<<<512, 256, 0, stream>>>(Wu, Wi, Wt_u, Wt_i);

    auto run_side = [&](const float* srcf, const float* tgtf, const int* edges, int E,
                        int N, const __hip_bfloat16* Wt, const float* bias, float* y) {
        const int* esrc = edges;
        const int* edst = edges + E;
        hipMemsetAsync(deg, 0, (size_t)N * sizeof(int), stream);
        hipMemsetAsync(cursor, 0, (size_t)N * sizeof(int), stream);
        k_hist<<<(E + 255) / 256, 256, 0, stream>>>(edst, E, deg);
        int nb = (N + 1023) / 1024;
        k_scan_block<<<nb, 1024, 0, stream>>>(deg, N, rs, bs);
        k_scan_sums<<<1, 1024, 0, stream>>>(bs, nb);
        k_finalize_rs<<<(N + 255) / 256, 256, 0, stream>>>(N, rs, bs);
        k_fill<<<(E + 255) / 256, 256, 0, stream>>>(esrc, edst, E, rs, cursor, csr);
        k_msg_x<<<(N + 3) / 4, 256, 0, stream>>>(srcf, tgtf, rs, csr, N, y);
        k_gemm_mfma_ln<<<(N + BM - 1) / BM, 256, 0, stream>>>(y, Wt, bias, gamma, beta, N, y);
    };

    run_side(itf, uf, iu_e, Eiu, NU, Wt_u, bu, u_out);
    run_side(uf, itf, ui_e, Eui, NI, Wt_i, bi, i_out);
}

// Round 5
// 219.193 us; speedup vs baseline: 1.4485x; 1.0044x over previous
//
#include <hip/hip_runtime.h>
#include <hip/hip_bf16.h>

#define D 256
#define BM 64
#define BK2 32
#define LDK2 40   // padded k-stride for BK=32 tiles (80 B rows, 16B-aligned)
#define LDK 72    // fallback-path pad

typedef __attribute__((ext_vector_type(8))) __bf16 bf16x8;
typedef __attribute__((ext_vector_type(4))) float f32x4;

__device__ __forceinline__ float bf2f(unsigned short u) {
    union { unsigned int i; float f; } c; c.i = ((unsigned int)u) << 16; return c.f;
}
__device__ __forceinline__ float bf2f_lo(unsigned int u) {
    union { unsigned int i; float f; } c; c.i = u << 16; return c.f;
}
__device__ __forceinline__ float bf2f_hi(unsigned int u) {
    union { unsigned int i; float f; } c; c.i = u & 0xffff0000u; return c.f;
}
__device__ __forceinline__ unsigned short f2bf(float f) {
    __hip_bfloat16 h = __float2bfloat16(f);
    return *reinterpret_cast<unsigned short*>(&h);
}
__device__ __forceinline__ unsigned int pack2(float lo, float hi) {
    return (unsigned int)f2bf(lo) | ((unsigned int)f2bf(hi) << 16);
}

// ======================= FAST PATH =======================

// blocks [0,nbF): features fp32->bf16 ; [nbF,nbF+512): W -> Wt[c][k] ; rest: zero deg
__global__ void k_cvt_all(const float* __restrict__ uf, const float* __restrict__ itf,
                          const float* __restrict__ Wu, const float* __restrict__ Wi,
                          unsigned short* __restrict__ feat_bf,
                          unsigned short* __restrict__ Wt_u, unsigned short* __restrict__ Wt_i,
                          int* __restrict__ deg, int Ntot,
                          size_t nfU, size_t nfTot, int nbF) {
    int b = blockIdx.x;
    if (b < nbF) {
        size_t base = ((size_t)b * 256 + threadIdx.x) * 8;
        if (base < nfTot) {
            const float* s = (base < nfU) ? (uf + base) : (itf + (base - nfU));
            float4 f0 = *(const float4*)s;
            float4 f1 = *(const float4*)(s + 4);
            ushort4 o0, o1;
            o0.x = f2bf(f0.x); o0.y = f2bf(f0.y); o0.z = f2bf(f0.z); o0.w = f2bf(f0.w);
            o1.x = f2bf(f1.x); o1.y = f2bf(f1.y); o1.z = f2bf(f1.z); o1.w = f2bf(f1.w);
            ((ushort4*)(feat_bf + base))[0] = o0;
            ((ushort4*)(feat_bf + base))[1] = o1;
        }
    } else if (b < nbF + 512) {
        int b2 = b - nbF;
        const float* W = (b2 < 256) ? Wu : Wi;
        unsigned short* Wt = (b2 < 256) ? Wt_u : Wt_i;
        int k = b2 & 255;
        int c = threadIdx.x;
        Wt[(size_t)c * 256 + k] = f2bf(W[(size_t)k * 256 + c]);
    } else {
        int zb = b - nbF - 512;
        size_t base = ((size_t)zb * 256 + threadIdx.x) * 4;
        if (base + 4 <= (size_t)Ntot) {
            *(int4*)(deg + base) = make_int4(0, 0, 0, 0);
        } else if (base < (size_t)Ntot) {
            for (size_t j = base; j < (size_t)Ntot; ++j) deg[j] = 0;
        }
    }
}

// degree histogram for both sides (unified deg[NU+NI])
__global__ void k_hist2(const int* __restrict__ iu_e, int Eiu,
                        const int* __restrict__ ui_e, int Eui,
                        int* __restrict__ deg, int NU) {
    int e = blockIdx.x * blockDim.x + threadIdx.x;
    if (e < Eiu) {
        atomicAdd(&deg[iu_e[Eiu + e]], 1);
    } else if (e < Eiu + Eui) {
        int e2 = e - Eiu;
        atomicAdd(&deg[NU + ui_e[Eui + e2]], 1);
    }
}

// per-1024-block inclusive scan of deg -> rs[i+1]; block totals -> bsums
__global__ void k_scan_block(const int* __restrict__ deg, int N,
                             int* __restrict__ rs, int* __restrict__ bsums) {
    __shared__ int s[1024];
    int base = blockIdx.x * 1024;
    int t = threadIdx.x;
    int v = (base + t < N) ? deg[base + t] : 0;
    s[t] = v;
    __syncthreads();
    for (int off = 1; off < 1024; off <<= 1) {
        int add = (t >= off) ? s[t - off] : 0;
        __syncthreads();
        s[t] += add;
        __syncthreads();
    }
    if (base + t < N) rs[base + t + 1] = s[t];
    if (t == 1023) bsums[blockIdx.x] = s[1023];
}

// exclusive scan of block sums (nb <= 1024)
__global__ void k_scan_sums(int* __restrict__ bsums, int nb) {
    __shared__ int s[1024];
    int t = threadIdx.x;
    int v = (t < nb) ? bsums[t] : 0;
    s[t] = v;
    __syncthreads();
    for (int off = 1; off < 1024; off <<= 1) {
        int add = (t >= off) ? s[t - off] : 0;
        __syncthreads();
        s[t] += add;
        __syncthreads();
    }
    if (t < nb) bsums[t] = s[t] - v;
}

// finalize rs and cursor: thread i owns rs[i+1], cur[i+1]; no races.
__global__ void k_finalize(int N, int* __restrict__ rs, int* __restrict__ cur,
                           const int* __restrict__ bsums) {
    int i = blockIdx.x * blockDim.x + threadIdx.x;
    if (i < N) {
        int v = rs[i + 1] + bsums[i >> 10];
        rs[i + 1] = v;
        cur[i + 1] = v;
    }
    if (i == 0) { rs[0] = 0; cur[0] = 0; }
}

// fill unified csr
__global__ void k_fill2(const int* __restrict__ iu_e, int Eiu,
                        const int* __restrict__ ui_e, int Eui,
                        int* __restrict__ cur, int NU,
                        int* __restrict__ csr) {
    int e = blockIdx.x * blockDim.x + threadIdx.x;
    if (e < Eiu) {
        int d = iu_e[Eiu + e];
        int p = atomicAdd(&cur[d], 1);
        csr[p] = iu_e[e];
    } else if (e < Eiu + Eui) {
        int e2 = e - Eiu;
        int d = ui_e[Eui + e2];
        int p = atomicAdd(&cur[NU + d], 1);
        csr[p] = ui_e[e2];
    }
}

// x = bf16( tgt + mean(src rows) ); TWO rows per wave (one per 32-lane half),
// each half-lane owns 8 bf16 (16 B); 4-unrolled gather -> up to 8 loads in flight.
__global__ void k_msg2(const unsigned short* __restrict__ uf_bf,
                       const unsigned short* __restrict__ if_bf,
                       const int* __restrict__ rs, const int* __restrict__ csr,
                       unsigned short* __restrict__ x_u, unsigned short* __restrict__ x_i,
                       int NU, int NI) {
    int pair = (blockIdx.x * blockDim.x + threadIdx.x) >> 6;
    int lane = threadIdx.x & 63;
    int half = lane >> 5;
    int hl   = lane & 31;
    int Ntot = NU + NI;
    int wv = pair * 2 + half;           // unified target row id (per half-wave)
    if (wv >= Ntot) return;

    const unsigned short* src; const unsigned short* tgt; unsigned short* xo; int w;
    if (wv < NU) { src = if_bf; tgt = uf_bf; xo = x_u; w = wv; }
    else         { src = uf_bf; tgt = if_bf; xo = x_i; w = wv - NU; }

    int s0 = rs[wv], s1 = rs[wv + 1];
    float a0[8] = {}, a1[8] = {}, a2[8] = {}, a3[8] = {};

    int i = s0;
    for (; i + 4 <= s1; i += 4) {
        int e0 = csr[i], e1 = csr[i + 1], e2 = csr[i + 2], e3 = csr[i + 3];
        uint4 r0 = ((const uint4*)(src + (size_t)e0 * D))[hl];
        uint4 r1 = ((const uint4*)(src + (size_t)e1 * D))[hl];
        uint4 r2 = ((const uint4*)(src + (size_t)e2 * D))[hl];
        uint4 r3 = ((const uint4*)(src + (size_t)e3 * D))[hl];
        a0[0] += bf2f_lo(r0.x); a0[1] += bf2f_hi(r0.x); a0[2] += bf2f_lo(r0.y); a0[3] += bf2f_hi(r0.y);
        a0[4] += bf2f_lo(r0.z); a0[5] += bf2f_hi(r0.z); a0[6] += bf2f_lo(r0.w); a0[7] += bf2f_hi(r0.w);
        a1[0] += bf2f_lo(r1.x); a1[1] += bf2f_hi(r1.x); a1[2] += bf2f_lo(r1.y); a1[3] += bf2f_hi(r1.y);
        a1[4] += bf2f_lo(r1.z); a1[5] += bf2f_hi(r1.z); a1[6] += bf2f_lo(r1.w); a1[7] += bf2f_hi(r1.w);
        a2[0] += bf2f_lo(r2.x); a2[1] += bf2f_hi(r2.x); a2[2] += bf2f_lo(r2.y); a2[3] += bf2f_hi(r2.y);
        a2[4] += bf2f_lo(r2.z); a2[5] += bf2f_hi(r2.z); a2[6] += bf2f_lo(r2.w); a2[7] += bf2f_hi(r2.w);
        a3[0] += bf2f_lo(r3.x); a3[1] += bf2f_hi(r3.x); a3[2] += bf2f_lo(r3.y); a3[3] += bf2f_hi(r3.y);
        a3[4] += bf2f_lo(r3.z); a3[5] += bf2f_hi(r3.z); a3[6] += bf2f_lo(r3.w); a3[7] += bf2f_hi(r3.w);
    }
    for (; i < s1; ++i) {
        int e0 = csr[i];
        uint4 r0 = ((const uint4*)(src + (size_t)e0 * D))[hl];
        a0[0] += bf2f_lo(r0.x); a0[1] += bf2f_hi(r0.x); a0[2] += bf2f_lo(r0.y); a0[3] += bf2f_hi(r0.y);
        a0[4] += bf2f_lo(r0.z); a0[5] += bf2f_hi(r0.z); a0[6] += bf2f_lo(r0.w); a0[7] += bf2f_hi(r0.w);
    }

    int cnt = s1 - s0;
    float inv = 1.0f / (float)(cnt > 0 ? cnt : 1);
    uint4 tv = ((const uint4*)(tgt + (size_t)w * D))[hl];
    float x0 = bf2f_lo(tv.x) + (a0[0] + a1[0] + a2[0] + a3[0]) * inv;
    float x1 = bf2f_hi(tv.x) + (a0[1] + a1[1] + a2[1] + a3[1]) * inv;
    float x2 = bf2f_lo(tv.y) + (a0[2] + a1[2] + a2[2] + a3[2]) * inv;
    float x3 = bf2f_hi(tv.y) + (a0[3] + a1[3] + a2[3] + a3[3]) * inv;
    float x4 = bf2f_lo(tv.z) + (a0[4] + a1[4] + a2[4] + a3[4]) * inv;
    float x5 = bf2f_hi(tv.z) + (a0[5] + a1[5] + a2[5] + a3[5]) * inv;
    float x6 = bf2f_lo(tv.w) + (a0[6] + a1[6] + a2[6] + a3[6]) * inv;
    float x7 = bf2f_hi(tv.w) + (a0[7] + a1[7] + a2[7] + a3[7]) * inv;
    uint4 o;
    o.x = pack2(x0, x1); o.y = pack2(x2, x3); o.z = pack2(x4, x5); o.w = pack2(x6, x7);
    ((uint4*)(xo + (size_t)w * D))[hl] = o;
}

// bf16-MFMA GEMM + bias + ReLU + LayerNorm; both sides, BK=32, reg-prefetched staging.
__launch_bounds__(256)
__global__ void k_gemm2(const unsigned short* __restrict__ x_u,
                        const unsigned short* __restrict__ x_i,
                        const unsigned short* __restrict__ Wt_u,
                        const unsigned short* __restrict__ Wt_i,
                        const float* __restrict__ bu, const float* __restrict__ bi,
                        const float* __restrict__ gamma, const float* __restrict__ beta,
                        int NU, int NI, int nbU, float* __restrict__ out) {
    __shared__ __hip_bfloat16 As[BM][LDK2];   // 5120 B
    __shared__ __hip_bfloat16 Bs[D][LDK2];    // 20480 B
    __shared__ float red_s[BM][4];
    __shared__ float red_q[BM][4];

    int b = blockIdx.x;
    bool isU = b < nbU;
    const unsigned short* X  = isU ? x_u : x_i;
    const unsigned short* Wt = isU ? Wt_u : Wt_i;
    const float* bias        = isU ? bu : bi;
    float* Y                 = isU ? out : out + (size_t)NU * D;
    int N                    = isU ? NU : NI;
    int row0 = (isU ? b : b - nbU) * BM;

    int t = threadIdx.x;
    int lane = t & 63;
    int w = t >> 6;
    int l15 = lane & 15;
    int l4 = lane >> 4;

    // staging addresses
    int ar = row0 + (t >> 2);              // A row for this thread
    int ak = (t & 3) * 8;                  // A k-offset (8 bf16 = 16 B)
    const uint4* Ag = (const uint4*)&X[(size_t)ar * D + ak];   // +k0/8 per tile
    const uint4* Bg = (const uint4*)&Wt[(size_t)t * D];        // col t; +k0/8

    uint4 uz = {0, 0, 0, 0};
    bool aok = (ar < N);
    // prologue: prefetch tile 0
    uint4 aR = aok ? Ag[0] : uz;
    uint4 bR0 = Bg[0], bR1 = Bg[1], bR2 = Bg[2], bR3 = Bg[3];

    f32x4 acc[4][4];
    f32x4 zero = {0.f, 0.f, 0.f, 0.f};
    #pragma unroll
    for (int fr = 0; fr < 4; fr++)
        #pragma unroll
        for (int fc = 0; fc < 4; fc++)
            acc[fr][fc] = zero;

    for (int k0 = 0; k0 < D; k0 += BK2) {
        // write staged regs to LDS
        *(uint4*)&As[t >> 2][ak] = aR;
        *(uint4*)&Bs[t][0]  = bR0;
        *(uint4*)&Bs[t][8]  = bR1;
        *(uint4*)&Bs[t][16] = bR2;
        *(uint4*)&Bs[t][24] = bR3;
        __syncthreads();
        // prefetch next tile (overlaps ds_read + MFMA below)
        if (k0 + BK2 < D) {
            int kn = (k0 + BK2) >> 3;
            aR  = aok ? Ag[kn] : uz;
            bR0 = Bg[kn]; bR1 = Bg[kn + 1]; bR2 = Bg[kn + 2]; bR3 = Bg[kn + 3];
        }
        bf16x8 af[4], bg4[4];
        #pragma unroll
        for (int fr = 0; fr < 4; fr++)
            af[fr] = *(const bf16x8*)&As[fr * 16 + l15][l4 * 8];
        #pragma unroll
        for (int fc = 0; fc < 4; fc++)
            bg4[fc] = *(const bf16x8*)&Bs[w * 64 + fc * 16 + l15][l4 * 8];
        #pragma unroll
        for (int fr = 0; fr < 4; fr++)
            #pragma unroll
            for (int fc = 0; fc < 4; fc++)
                acc[fr][fc] = __builtin_amdgcn_mfma_f32_16x16x32_bf16(
                    af[fr], bg4[fc], acc[fr][fc], 0, 0, 0);
        __syncthreads();
    }

    // epilogue: bias + relu + LN
    float bias_c[4], gam_c[4], bet_c[4];
    #pragma unroll
    for (int fc = 0; fc < 4; fc++) {
        int col = w * 64 + fc * 16 + l15;
        bias_c[fc] = bias[col];
        gam_c[fc]  = gamma[col];
        bet_c[fc]  = beta[col];
    }

    #pragma unroll
    for (int fr = 0; fr < 4; fr++) {
        #pragma unroll
        for (int r = 0; r < 4; r++) {
            int row = fr * 16 + l4 * 4 + r;
            float s = 0.f, q = 0.f;
            #pragma unroll
            for (int fc = 0; fc < 4; fc++) {
                float v = acc[fr][fc][r] + bias_c[fc];
                v = fmaxf(v, 0.f);
                acc[fr][fc][r] = v;
                s += v;
                q += v * v;
            }
            #pragma unroll
            for (int m = 1; m < 16; m <<= 1) {
                s += __shfl_xor(s, m);
                q += __shfl_xor(q, m);
            }
            if (l15 == 0) { red_s[row][w] = s; red_q[row][w] = q; }
        }
    }
    __syncthreads();

    #pragma unroll
    for (int fr = 0; fr < 4; fr++) {
        #pragma unroll
        for (int r = 0; r < 4; r++) {
            int row = fr * 16 + l4 * 4 + r;
            int grow = row0 + row;
            if (grow >= N) continue;
            float s = red_s[row][0] + red_s[row][1] + red_s[row][2] + red_s[row][3];
            float q = red_q[row][0] + red_q[row][1] + red_q[row][2] + red_q[row][3];
            float mu  = s * (1.0f / 256.0f);
            float var = q * (1.0f / 256.0f) - mu * mu;
            float rstd = rsqrtf(var + 1e-5f);
            #pragma unroll
            for (int fc = 0; fc < 4; fc++) {
                int col = w * 64 + fc * 16 + l15;
                Y[(size_t)grow * D + col] = (acc[fr][fc][r] - mu) * rstd * gam_c[fc] + bet_c[fc];
            }
        }
    }
}

// ======================= FALLBACK PATH (R2, small-ws) =======================

__global__ void k_hist(const int* __restrict__ dst, int E, int* __restrict__ deg) {
    int e = blockIdx.x * blockDim.x + threadIdx.x;
    if (e < E) atomicAdd(&deg[dst[e]], 1);
}

__global__ void k_finalize_rs(int N, int* __restrict__ rs, const int* __restrict__ bsums) {
    int i = blockIdx.x * blockDim.x + threadIdx.x;
    if (i < N) rs[i + 1] += bsums[i >> 10];
    if (i == 0) rs[0] = 0;
}

__global__ void k_fill(const int* __restrict__ src, const int* __restrict__ dst, int E,
                       const int* __restrict__ rs, int* __restrict__ cursor,
                       int* __restrict__ csr) {
    int e = blockIdx.x * blockDim.x + threadIdx.x;
    if (e < E) {
        int d = dst[e];
        int p = atomicAdd(&cursor[d], 1);
        csr[rs[d] + p] = src[e];
    }
}

__global__ void k_msg_x(const float* __restrict__ srcf, const float* __restrict__ tgtf,
                        const int* __restrict__ rs, const int* __restrict__ csr,
                        int N, float* __restrict__ xout) {
    int wave = (blockIdx.x * blockDim.x + threadIdx.x) >> 6;
    int lane = threadIdx.x & 63;
    if (wave >= N) return;
    int s0 = rs[wave], s1 = rs[wave + 1];
    float4 acc = make_float4(0.f, 0.f, 0.f, 0.f);
    for (int i = s0; i < s1; i++) {
        int s = csr[i];
        float4 f = *(const float4*)&srcf[(size_t)s * D + lane * 4];
        acc.x += f.x; acc.y += f.y; acc.z += f.z; acc.w += f.w;
    }
    int cnt = s1 - s0;
    float inv = 1.0f / (float)(cnt > 0 ? cnt : 1);
    float4 t = *(const float4*)&tgtf[(size_t)wave * D + lane * 4];
    float4 x;
    x.x = t.x + acc.x * inv;
    x.y = t.y + acc.y * inv;
    x.z = t.z + acc.z * inv;
    x.w = t.w + acc.w * inv;
    *(float4*)&xout[(size_t)wave * D + lane * 4] = x;
}

__global__ void k_wcvt(const float* __restrict__ W0, const float* __restrict__ W1,
                       __hip_bfloat16* __restrict__ Wt0, __hip_bfloat16* __restrict__ Wt1) {
    int b = blockIdx.x;
    const float* W = (b < 256) ? W0 : W1;
    __hip_bfloat16* Wt = (b < 256) ? Wt0 : Wt1;
    int k = b & 255;
    int c = threadIdx.x;
    Wt[(size_t)c * 256 + k] = __float2bfloat16(W[(size_t)k * 256 + c]);
}

__launch_bounds__(256)
__global__ void k_gemm_mfma_ln(const float* __restrict__ X,
                               const __hip_bfloat16* __restrict__ Wt,
                               const float* __restrict__ bias,
                               const float* __restrict__ gamma,
                               const float* __restrict__ beta,
                               int N, float* __restrict__ Y) {
    __shared__ __hip_bfloat16 As[BM][LDK];
    __shared__ __hip_bfloat16 Bs[D][LDK];
    __shared__ float red_s[BM][4];
    __shared__ float red_q[BM][4];

    int t = threadIdx.x;
    int lane = t & 63;
    int w = t >> 6;
    int l15 = lane & 15;
    int l4 = lane >> 4;
    int row0 = blockIdx.x * BM;

    f32x4 acc[4][4];
    f32x4 zero = {0.f, 0.f, 0.f, 0.f};
    #pragma unroll
    for (int fr = 0; fr < 4; fr++)
        #pragma unroll
        for (int fc = 0; fc < 4; fc++)
            acc[fr][fc] = zero;

    for (int k0 = 0; k0 < D; k0 += 64) {
        {
            int i = t >> 2;
            int kq = (t & 3) * 16;
            int r = row0 + i;
            float4 f[4];
            if (r < N) {
                const float4* p = (const float4*)&X[(size_t)r * D + k0 + kq];
                f[0] = p[0]; f[1] = p[1]; f[2] = p[2]; f[3] = p[3];
            } else {
                float4 z4 = make_float4(0.f, 0.f, 0.f, 0.f);
                f[0] = z4; f[1] = z4; f[2] = z4; f[3] = z4;
            }
            __hip_bfloat16 vb[16];
            #pragma unroll
            for (int q = 0; q < 4; q++) {
                vb[q * 4 + 0] = __float2bfloat16(f[q].x);
                vb[q * 4 + 1] = __float2bfloat16(f[q].y);
                vb[q * 4 + 2] = __float2bfloat16(f[q].z);
                vb[q * 4 + 3] = __float2bfloat16(f[q].w);
            }
            *(uint4*)&As[i][kq]     = *(uint4*)&vb[0];
            *(uint4*)&As[i][kq + 8] = *(uint4*)&vb[8];
        }
        #pragma unroll
        for (int pass = 0; pass < 4; pass++) {
            int c = pass * 64 + (t >> 2);
            int kq = (t & 3) * 16;
            const uint4* p = (const uint4*)&Wt[(size_t)c * D + k0 + kq];
            uint4 b0 = p[0], b1 = p[1];
            *(uint4*)&Bs[c][kq]     = b0;
            *(uint4*)&Bs[c][kq + 8] = b1;
        }
        __syncthreads();

        #pragma unroll
        for (int ks = 0; ks < 2; ks++) {
            bf16x8 af[4], bg[4];
            #pragma unroll
            for (int fr = 0; fr < 4; fr++)
                af[fr] = *(const bf16x8*)&As[fr * 16 + l15][ks * 32 + l4 * 8];
            #pragma unroll
            for (int fc = 0; fc < 4; fc++)
                bg[fc] = *(const bf16x8*)&Bs[w * 64 + fc * 16 + l15][ks * 32 + l4 * 8];
            #pragma unroll
            for (int fr = 0; fr < 4; fr++)
                #pragma unroll
                for (int fc = 0; fc < 4; fc++)
                    acc[fr][fc] = __builtin_amdgcn_mfma_f32_16x16x32_bf16(
                        af[fr], bg[fc], acc[fr][fc], 0, 0, 0);
        }
        __syncthreads();
    }

    float bias_c[4], gam_c[4], bet_c[4];
    #pragma unroll
    for (int fc = 0; fc < 4; fc++) {
        int col = w * 64 + fc * 16 + l15;
        bias_c[fc] = bias[col];
        gam_c[fc]  = gamma[col];
        bet_c[fc]  = beta[col];
    }

    #pragma unroll
    for (int fr = 0; fr < 4; fr++) {
        #pragma unroll
        for (int r = 0; r < 4; r++) {
            int row = fr * 16 + l4 * 4 + r;
            float s = 0.f, q = 0.f;
            #pragma unroll
            for (int fc = 0; fc < 4; fc++) {
                float v = acc[fr][fc][r] + bias_c[fc];
                v = fmaxf(v, 0.f);
                acc[fr][fc][r] = v;
                s += v;
                q += v * v;
            }
            #pragma unroll
            for (int m = 1; m < 16; m <<= 1) {
                s += __shfl_xor(s, m);
                q += __shfl_xor(q, m);
            }
            if (l15 == 0) { red_s[row][w] = s; red_q[row][w] = q; }
        }
    }
    __syncthreads();

    #pragma unroll
    for (int fr = 0; fr < 4; fr++) {
        #pragma unroll
        for (int r = 0; r < 4; r++) {
            int row = fr * 16 + l4 * 4 + r;
            int grow = row0 + row;
            if (grow >= N) continue;
            float s = red_s[row][0] + red_s[row][1] + red_s[row][2] + red_s[row][3];
            float q = red_q[row][0] + red_q[row][1] + red_q[row][2] + red_q[row][3];
            float mu  = s * (1.0f / 256.0f);
            float var = q * (1.0f / 256.0f) - mu * mu;
            float rstd = rsqrtf(var + 1e-5f);
            #pragma unroll
            for (int fc = 0; fc < 4; fc++) {
                int col = w * 64 + fc * 16 + l15;
                Y[(size_t)grow * D + col] = (acc[fr][fc][r] - mu) * rstd * gam_c[fc] + bet_c[fc];
            }
        }
    }
}

// ======================= launch =======================

extern "C" void kernel_launch(void* const* d_in, const int* in_sizes, int n_in,
                              void* d_out, int out_size, void* d_ws, size_t ws_size,
                              hipStream_t stream) {
    const float* uf    = (const float*)d_in[0];
    const float* itf   = (const float*)d_in[1];
    const int*   ui_e  = (const int*)d_in[2];   // [2, Eui] user->item
    const int*   iu_e  = (const int*)d_in[3];   // [2, Eiu] item->user
    const float* Wu    = (const float*)d_in[4];
    const float* bu    = (const float*)d_in[5];
    const float* Wi    = (const float*)d_in[6];
    const float* bi    = (const float*)d_in[7];
    const float* gamma = (const float*)d_in[8];
    const float* beta  = (const float*)d_in[9];

    int NU  = in_sizes[0] / D;
    int NI  = in_sizes[1] / D;
    int Eui = in_sizes[2] / 2;
    int Eiu = in_sizes[3] / 2;
    int Nmax = NU > NI ? NU : NI;
    int Ntot = NU + NI;
    int Etot = Eiu + Eui;

    float* out   = (float*)d_out;
    size_t nfU = (size_t)NU * D;
    size_t nfI = (size_t)NI * D;
    size_t nfTot = nfU + nfI;

    // fast-path ws layout
    unsigned short* uf_bf = (unsigned short*)d_ws;     // nfU
    unsigned short* if_bf = uf_bf + nfU;               // nfI
    unsigned short* x_u   = if_bf + nfI;               // nfU
    unsigned short* x_i   = x_u + nfU;                 // nfI
    unsigned short* Wt_u2 = x_i + nfI;                 // 65536
    unsigned short* Wt_i2 = Wt_u2 + 65536;             // 65536
    int* deg2  = (int*)(Wt_i2 + 65536);                // Ntot
    int* rs2   = deg2 + Ntot;                          // Ntot+1
    int* cur2  = rs2 + Ntot + 1;                       // Ntot+1
    int* bsums = cur2 + Ntot + 1;                      // 1024
    int* csr2  = bsums + 1024;                         // Etot
    size_t needed = (size_t)((char*)(csr2 + Etot) - (char*)d_ws);

    if (ws_size >= needed) {
        int nbF = (int)((nfTot + 2047) / 2048);
        int nbZ = (Ntot + 1023) / 1024;
        k_cvt_all<<<nbF + 512 + nbZ, 256, 0, stream>>>(uf, itf, Wu, Wi, uf_bf, Wt_u2, Wt_i2,
                                                       deg2, Ntot, nfU, nfTot, nbF);
        k_hist2<<<(Etot + 255) / 256, 256, 0, stream>>>(iu_e, Eiu, ui_e, Eui, deg2, NU);
        int nb = (Ntot + 1023) / 1024;
        k_scan_block<<<nb, 1024, 0, stream>>>(deg2, Ntot, rs2, bsums);
        k_scan_sums<<<1, 1024, 0, stream>>>(bsums, nb);
        k_finalize<<<(Ntot + 255) / 256, 256, 0, stream>>>(Ntot, rs2, cur2, bsums);
        k_fill2<<<(Etot + 255) / 256, 256, 0, stream>>>(iu_e, Eiu, ui_e, Eui, cur2, NU, csr2);
        int pairs = (Ntot + 1) / 2;
        k_msg2<<<(pairs + 3) / 4, 256, 0, stream>>>(uf_bf, if_bf, rs2, csr2, x_u, x_i, NU, NI);
        int nbU = (NU + BM - 1) / BM;
        int nbI = (NI + BM - 1) / BM;
        k_gemm2<<<nbU + nbI, 256, 0, stream>>>(x_u, x_i, Wt_u2, Wt_i2, bu, bi, gamma, beta,
                                               NU, NI, nbU, out);
        return;
    }

    // ---------- fallback: R2 path (needs ~2.2 MB ws) ----------
    float* u_out = out;
    float* i_out = out + nfU;
    __hip_bfloat16* Wt_u = (__hip_bfloat16*)d_ws;
    __hip_bfloat16* Wt_i = Wt_u + 256 * 256;
    int* deg    = (int*)(Wt_i + 256 * 256);
    int* rs     = deg + Nmax;
    int* bs     = rs + Nmax + 1;
    int* cursor = bs + 1024;
    int* csr    = cursor + Nmax;

    k_wcvt<<<512, 256, 0, stream>>>(Wu, Wi, Wt_u, Wt_i);

    auto run_side = [&](const float* srcf, const float* tgtf, const int* edges, int E,
                        int N, const __hip_bfloat16* Wt, const float* bias, float* y) {
        const int* esrc = edges;
        const int* edst = edges + E;
        hipMemsetAsync(deg, 0, (size_t)N * sizeof(int), stream);
        hipMemsetAsync(cursor, 0, (size_t)N * sizeof(int), stream);
        k_hist<<<(E + 255) / 256, 256, 0, stream>>>(edst, E, deg);
        int nb = (N + 1023) / 1024;
        k_scan_block<<<nb, 1024, 0, stream>>>(deg, N, rs, bs);
        k_scan_sums<<<1, 1024, 0, stream>>>(bs, nb);
        k_finalize_rs<<<(N + 255) / 256, 256, 0, stream>>>(N, rs, bs);
        k_fill<<<(E + 255) / 256, 256, 0, stream>>>(esrc, edst, E, rs, cursor, csr);
        k_msg_x<<<(N + 3) / 4, 256, 0, stream>>>(srcf, tgtf, rs, csr, N, y);
        k_gemm_mfma_ln<<<(N + BM - 1) / BM, 256, 0, stream>>>(y, Wt, bias, gamma, beta, N, y);
    };

    run_side(itf, uf, iu_e, Eiu, NU, Wt_u, bu, u_out);
    run_side(uf, itf, ui_e, Eui, NI, Wt_i, bi, i_out);
}